// Round 3
// baseline (282.240 us; speedup 1.0000x reference)
//
#include <hip/hip_runtime.h>
#include <hip/hip_bf16.h>

// B=2, T=2048, E=1024, H=16, D=64. Inputs f32 (+ int32 mask), output f32.
// Internal bf16 MFMA pipeline.
// prep: ONE dispatch = embed f32->bf16 convert + 4x weight transpose+cast
//       + mask int32 -> 1-bit bitmask (1MB, L2-resident).
// GEMMs: round-7 ASYNC16 2-barrier structure verbatim (known good).
// Flash THIS ROUND: wave-pair key-split at 512 threads (round-2's partition
//   -- verified correct -- but with the register budget that round 2 lacked:
//   1024-thr blocks forced VGPR=32 + 14.5MB scratch spills; 512-thr blocks
//   with q-tile 64 keep per-wave state ~48 VGPR under the 64 cap).
//   8 waves = 4 strips x 2 key-halves; grid (T/64,H,B)=1024 blocks = exactly
//   4 blocks/CU; LDS trimmed to exactly 40960B (P pad-72 -> XOR-swizzled
//   stride 64) so 4x40KB = 160KiB fits. 32 waves/CU (was 16), per-wave
//   chain halved, no spills, no tail.

typedef __bf16 bf8_t  __attribute__((ext_vector_type(8)));
typedef __bf16 bf4_t  __attribute__((ext_vector_type(4)));
typedef float  f4_t   __attribute__((ext_vector_type(4)));

constexpr int Bb = 2, Tt = 2048, Hh = 16, Dd = 64;

#define ASYNC16(g, l)                                                        \
    __builtin_amdgcn_global_load_lds(                                        \
        (const __attribute__((address_space(1))) void*)(g),                  \
        (__attribute__((address_space(3))) void*)(l), 16, 0, 0)

#if __has_builtin(__builtin_amdgcn_exp2f)
#define EXP2F(x) __builtin_amdgcn_exp2f(x)
#else
#define EXP2F(x) exp2f(x)
#endif

// ---------------------------------------------------------------- prep
// blockIdx.x decode: [0,4096) transpose W (z>>10 = which matrix),
// [4096,5120) convert embed, [5120,6144) build bitmask.
__global__ __launch_bounds__(256) void prep_kernel(
    const float* __restrict__ embed, const int* __restrict__ mask,
    const float* __restrict__ w0, const float* __restrict__ w1,
    const float* __restrict__ w2, const float* __restrict__ w3,
    __bf16* __restrict__ o0, __bf16* __restrict__ o1,
    __bf16* __restrict__ o2, __bf16* __restrict__ o3,
    __bf16* __restrict__ Eb, unsigned* __restrict__ Mbits)
{
    int z = blockIdx.x;
    if (z < 4096) {
        const float* in; __bf16* out;
        switch (z >> 10) {
            case 0: in = w0; out = o0; break;
            case 1: in = w1; out = o1; break;
            case 2: in = w2; out = o2; break;
            default: in = w3; out = o3; break;
        }
        int rem = z & 1023;
        int bx = (rem & 31) * 32;      // n offset
        int by = (rem >> 5) * 32;      // k offset
        __shared__ float t[32][33];
        int x  = threadIdx.x & 31;
        int y0 = threadIdx.x >> 5;
        #pragma unroll
        for (int i = 0; i < 4; i++) {
            int y = y0 + i * 8;
            t[y][x] = in[(size_t)(by + y) * 1024 + bx + x];
        }
        __syncthreads();
        #pragma unroll
        for (int i = 0; i < 4; i++) {
            int y = y0 + i * 8;
            out[(size_t)(bx + y) * 1024 + by + x] = (__bf16)t[x][y];
        }
    } else if (z < 5120) {
        size_t base = (size_t)(z - 4096) * 4096;
        #pragma unroll
        for (int j = 0; j < 4; j++) {
            size_t i = base + j * 1024 + threadIdx.x * 4;
            float4 v = *reinterpret_cast<const float4*>(embed + i);
            bf4_t o = {(__bf16)v.x, (__bf16)v.y, (__bf16)v.z, (__bf16)v.w};
            *reinterpret_cast<bf4_t*>(Eb + i) = o;
        }
    } else {
        // word g covers mask[g*32 .. g*32+32)
        size_t g = (size_t)(z - 5120) * 256 + threadIdx.x;
        const int* mp = mask + g * 32;
        unsigned v = 0;
        #pragma unroll
        for (int i = 0; i < 8; i++) {
            int4 m4 = *reinterpret_cast<const int4*>(mp + i * 4);
            if (m4.x) v |= 1u << (i * 4 + 0);
            if (m4.y) v |= 1u << (i * 4 + 1);
            if (m4.z) v |= 1u << (i * 4 + 2);
            if (m4.w) v |= 1u << (i * 4 + 3);
        }
        Mbits[g] = v;
    }
}

// ---------------------------------------------------------------- GEMM body
// round-7 structure verbatim: ASYNC16 staging, 2 barriers/iter, XOR swizzle.
template <int TM, typename OutT>
__device__ __forceinline__ void gemm_body(const __bf16* __restrict__ A,
                                          const __bf16* __restrict__ Bt,
                                          const float* __restrict__ bias,
                                          OutT* __restrict__ out,
                                          int mode, float oscale, int bx, int by)
{
    constexpr int NI = TM / 32;
    alignas(16) __shared__ __bf16 As[TM * 64];
    alignas(16) __shared__ __bf16 Bs[128 * 64];

    int tid  = threadIdx.x;
    int lane = tid & 63;
    int quad = lane >> 4;
    int l16  = lane & 15;
    int wave = tid >> 6;
    int wm   = wave >> 1, wn = wave & 1;

    f4_t acc[NI][4];
    #pragma unroll
    for (int i = 0; i < NI; i++)
        #pragma unroll
        for (int j = 0; j < 4; j++)
            acc[i][j] = f4_t{0.f, 0.f, 0.f, 0.f};

    for (int kt = 0; kt < 1024; kt += 64) {
        #pragma unroll
        for (int i = 0; i < TM / 32; i++) {
            int c   = tid + 256 * i;
            int row = c >> 3, j = c & 7;
            ASYNC16(A + (size_t)(by * TM + row) * 1024 + kt + ((j ^ (row & 7)) * 8),
                    &As[c * 8]);
        }
        #pragma unroll
        for (int i = 0; i < 4; i++) {
            int c   = tid + 256 * i;
            int row = c >> 3, j = c & 7;
            ASYNC16(Bt + (size_t)(bx * 128 + row) * 1024 + kt + ((j ^ (row & 7)) * 8),
                    &Bs[c * 8]);
        }
        __syncthreads();

        bf8_t af[2][NI], bfr[2][4];
        #pragma unroll
        for (int c = 0; c < 2; c++) {
            #pragma unroll
            for (int im = 0; im < NI; im++) {
                int row = wm * (TM / 2) + im * 16 + l16;
                af[c][im] = *reinterpret_cast<const bf8_t*>(
                    &As[row * 64 + (((c * 4 + quad) ^ (row & 7)) * 8)]);
            }
            #pragma unroll
            for (int in_ = 0; in_ < 4; in_++) {
                int row = wn * 64 + in_ * 16 + l16;
                bfr[c][in_] = *reinterpret_cast<const bf8_t*>(
                    &Bs[row * 64 + (((c * 4 + quad) ^ (row & 7)) * 8)]);
            }
        }
        #pragma unroll
        for (int c = 0; c < 2; c++)
            #pragma unroll
            for (int im = 0; im < NI; im++)
                #pragma unroll
                for (int in_ = 0; in_ < 4; in_++)
                    acc[im][in_] = __builtin_amdgcn_mfma_f32_16x16x32_bf16(
                        af[c][im], bfr[c][in_], acc[im][in_], 0, 0, 0);
        __syncthreads();
    }

    #pragma unroll
    for (int im = 0; im < NI; im++) {
        #pragma unroll
        for (int in_ = 0; in_ < 4; in_++) {
            int gc  = bx * 128 + wn * 64 + in_ * 16 + l16;
            float bb = bias[gc];
            int gr0 = by * TM + wm * (TM / 2) + im * 16 + quad * 4;
            if (mode == 2) {
                int b = gr0 >> 11, t0 = gr0 & 2047;
                int h = gc >> 6,  d = gc & 63;
                bf4_t ov;
                #pragma unroll
                for (int r = 0; r < 4; r++)
                    ov[r] = (__bf16)(acc[im][in_][r] + bb);
                *reinterpret_cast<bf4_t*>(
                    (__bf16*)out + ((size_t)(b * Hh + h) * Dd + d) * Tt + t0) = ov;
            } else {
                #pragma unroll
                for (int r = 0; r < 4; r++) {
                    int gr  = gr0 + r;
                    float v = (acc[im][in_][r] + bb) * oscale;
                    size_t idx;
                    if (mode == 0) {
                        idx = (size_t)gr * 1024 + gc;
                    } else {
                        int b = gr >> 11, t = gr & 2047;
                        int h = gc >> 6,  d = gc & 63;
                        idx = ((size_t)(b * Hh + h) * Tt + t) * Dd + d;
                    }
                    out[idx] = (OutT)v;
                }
            }
        }
    }
}

__global__ __launch_bounds__(256) void gemm_qkv_kernel(
    const __bf16* __restrict__ A,
    const __bf16* __restrict__ WqT, const __bf16* __restrict__ WkT, const __bf16* __restrict__ WvT,
    const float* __restrict__ bq,  const float* __restrict__ bk,  const float* __restrict__ bv,
    __bf16* __restrict__ Qo, __bf16* __restrict__ Ko, __bf16* __restrict__ Vo)
{
    const __bf16* Bt; const float* bias; __bf16* out; int mode; float sc;
    // Q carries 0.125 * log2(e) so flash softmax runs in exp2 domain.
    if      (blockIdx.z == 0) { Bt = WqT; bias = bq; out = Qo; mode = 1; sc = 0.18033688011112042f; }
    else if (blockIdx.z == 1) { Bt = WkT; bias = bk; out = Ko; mode = 1; sc = 1.f; }
    else                      { Bt = WvT; bias = bv; out = Vo; mode = 2; sc = 1.f; }
    gemm_body<128, __bf16>(A, Bt, bias, out, mode, sc, blockIdx.x, blockIdx.y);
}

__global__ __launch_bounds__(256) void gemm_out_kernel(
    const __bf16* __restrict__ A, const __bf16* __restrict__ Bt,
    const float* __restrict__ bias, float* __restrict__ out)
{
    gemm_body<64, float>(A, Bt, bias, out, 0, 1.f, blockIdx.x, blockIdx.y);
}

// ---------------------------------------------------------------- flash attn
// Wave-pair key-split, 512 thr = 8 waves. grid (T/64, H, B) = 1024 blocks.
// wave w: q-strip s = w>>1 (16 rows), key-half hk = w&1 (32 of 64 keys).
// LDS exactly 40960B -> 4 blocks/CU = 32 waves/CU:
//   Ks[2][64*64] 16KB | Vs[2][64*64] 16KB | P[4 strips][16*64] 8KB (XOR swz)
// Dbuf K/V, one barrier/iter, reg-staged prefetch after the barrier.
// P is intra-wave (own 32-col half) -> no extra barriers.
// Partial O/l pair-combined via LDS (reusing K/V region) at the end.
__global__ __launch_bounds__(512, 8) void flash_kernel(
    const __bf16* __restrict__ Qb, const __bf16* __restrict__ Kb,
    const __bf16* __restrict__ Vb, const unsigned* __restrict__ Mbits,
    __bf16* __restrict__ Zb)
{
    alignas(16) __shared__ char smem[40960];
    __bf16* Ks  = (__bf16*)smem;
    __bf16* Vs  = (__bf16*)(smem + 16384);
    char*   Pb  = smem + 32768;          // byte-addressed, XOR-swizzled
    float*  fscr = (float*)smem;         // epilogue reuse of K/V region

    int tid  = threadIdx.x;
    int lane = tid & 63;
    int wave = tid >> 6;        // 0..7
    int s    = wave >> 1;       // q-strip 0..3
    int hk   = wave & 1;        // key half
    int quad = lane >> 4;
    int l16  = lane & 15;
    int b = blockIdx.z, h = blockIdx.y;
    int bh = b * Hh + h;
    int qrow = blockIdx.x * 64 + s * 16;

    // staging: 512 threads cover one 64x64 tile; each thread 16B K + 16B V
    int srow = tid >> 3, sj = tid & 7;
    const __bf16* kgp = Kb + ((size_t)bh * Tt + srow) * Dd + ((sj ^ (srow & 7)) * 8);
    const __bf16* vgp = Vb + ((size_t)bh * Dd + srow) * Tt + ((sj ^ (srow & 7)) * 8);
    const int sdst = tid * 8;

    bf8_t qf[2];
    #pragma unroll
    for (int c = 0; c < 2; c++)
        qf[c] = *reinterpret_cast<const bf8_t*>(
            Qb + ((size_t)bh * Tt + qrow + l16) * Dd + c * 32 + quad * 8);

    // ones-fragment for the l_i row-sum MFMA
    bf8_t ones;
    #pragma unroll
    for (int i = 0; i < 8; i++) ones[i] = (__bf16)1.0f;

    // bitmask row for this lane's query
    const unsigned* bmp = Mbits + ((size_t)b * Tt + qrow + l16) * 64;

    // P byte offsets (stride 64 bf16 = 128B/row, XOR swizzle on 16B slots).
    // write n2: col2 = hk*64 + n2*32 + quad*8 (bf4); read: col2 = hk*64+quad*16 (bf8)
    char* pws = Pb + s * 2048;
    const int pw0 = l16 * 128 + ((hk * 64 + quad * 8)      ^ ((l16 & 7) << 4));
    const int pw1 = l16 * 128 + ((hk * 64 + 32 + quad * 8) ^ ((l16 & 7) << 4));
    const int prd = l16 * 128 + ((hk * 64 + quad * 16)     ^ ((l16 & 7) << 4));

    f4_t lacc = f4_t{0.f, 0.f, 0.f, 0.f};
    f4_t o[4];
    #pragma unroll
    for (int d = 0; d < 4; d++) o[d] = f4_t{0.f, 0.f, 0.f, 0.f};

    // prime: tile 0 into regs
    bf8_t kreg = *reinterpret_cast<const bf8_t*>(kgp);
    bf8_t vreg = *reinterpret_cast<const bf8_t*>(vgp);
    unsigned long long mreg = *reinterpret_cast<const unsigned long long*>(bmp);

    for (int kt = 0; kt < Tt; kt += 64) {
        int par = (kt >> 6) & 1;
        *reinterpret_cast<bf8_t*>(&Ks[par * 4096 + sdst]) = kreg;
        *reinterpret_cast<bf8_t*>(&Vs[par * 4096 + sdst]) = vreg;
        // this wave's mask nibbles (keys hk*32 + n2*16 + quad*4 + r)
        unsigned nib0 = (unsigned)(mreg >> (hk * 32 + quad * 4)) & 0xFu;
        unsigned nib1 = (unsigned)(mreg >> (hk * 32 + 16 + quad * 4)) & 0xFu;
        __syncthreads();

        // prefetch next tile (issued after barrier -> hidden under compute)
        int ktn = (kt + 64 < Tt) ? kt + 64 : 0;
        kreg = *reinterpret_cast<const bf8_t*>(kgp + (size_t)ktn * Dd);
        vreg = *reinterpret_cast<const bf8_t*>(vgp + ktn);
        mreg = *reinterpret_cast<const unsigned long long*>(bmp + (ktn >> 5));

        // S^T = K Q^T over this wave's 32 keys: 2 key-subtiles x 2 d-chunks
        f4_t sA = f4_t{0.f, 0.f, 0.f, 0.f};
        f4_t sB = f4_t{0.f, 0.f, 0.f, 0.f};
        __builtin_amdgcn_s_setprio(1);
        #pragma unroll
        for (int c = 0; c < 2; c++) {
            int krow0 = hk * 32 + l16;
            bf8_t kf0 = *reinterpret_cast<const bf8_t*>(
                &Ks[par * 4096 + krow0 * 64 + (((c * 4 + quad) ^ (krow0 & 7)) * 8)]);
            sA = __builtin_amdgcn_mfma_f32_16x16x32_bf16(kf0, qf[c], sA, 0, 0, 0);
            int krow1 = hk * 32 + 16 + l16;
            bf8_t kf1 = *reinterpret_cast<const bf8_t*>(
                &Ks[par * 4096 + krow1 * 64 + (((c * 4 + quad) ^ (krow1 & 7)) * 8)]);
            sB = __builtin_amdgcn_mfma_f32_16x16x32_bf16(kf1, qf[c], sB, 0, 0, 0);
        }
        __builtin_amdgcn_s_setprio(0);

        // p = mask-bit ? exp2(s) : 0 ; write this wave's 32-col P half
        {
            bf4_t pv4;
            #pragma unroll
            for (int r = 0; r < 4; r++) {
                float p = (nib0 & (1u << r)) ? EXP2F(sA[r]) : 0.f;
                pv4[r] = (__bf16)p;
            }
            *reinterpret_cast<bf4_t*>(pws + pw0) = pv4;
            #pragma unroll
            for (int r = 0; r < 4; r++) {
                float p = (nib1 & (1u << r)) ? EXP2F(sB[r]) : 0.f;
                pv4[r] = (__bf16)p;
            }
            *reinterpret_cast<bf4_t*>(pws + pw1) = pv4;
        }

        // O_half += V^T @ P_half ; l_half += ones @ P_half (intra-wave LDS dep)
        bf8_t pf = *reinterpret_cast<const bf8_t*>(pws + prd);
        __builtin_amdgcn_s_setprio(1);
        lacc = __builtin_amdgcn_mfma_f32_16x16x32_bf16(ones, pf, lacc, 0, 0, 0);
        #pragma unroll
        for (int ds = 0; ds < 4; ds++) {
            int vrow = ds * 16 + l16;
            bf8_t vf = *reinterpret_cast<const bf8_t*>(
                &Vs[par * 4096 + vrow * 64 + (((hk * 4 + quad) ^ (vrow & 7)) * 8)]);
            o[ds] = __builtin_amdgcn_mfma_f32_16x16x32_bf16(vf, pf, o[ds], 0, 0, 0);
        }
        __builtin_amdgcn_s_setprio(0);
        // no trailing barrier: next iter writes the other buffer.
    }

    // pair-combine: hk=1 wave dumps partial O and l to LDS; hk=0 adds + stores
    __syncthreads();
    float* wsp = fscr + s * (64 * 20);
    if (hk) {
        #pragma unroll
        for (int ds = 0; ds < 4; ds++)
            *reinterpret_cast<f4_t*>(&wsp[lane * 20 + ds * 4]) = o[ds];
        wsp[lane * 20 + 16] = lacc[0];
    }
    __syncthreads();
    if (!hk) {
        #pragma unroll
        for (int ds = 0; ds < 4; ds++) {
            f4_t op = *reinterpret_cast<const f4_t*>(&wsp[lane * 20 + ds * 4]);
            o[ds] += op;
        }
        float l = lacc[0] + wsp[lane * 20 + 16];
        float inv = 1.f / fmaxf(l, 1e-30f);
        size_t zrow = ((size_t)b * Tt + qrow + l16) * 1024 + h * 64;
        #pragma unroll
        for (int ds = 0; ds < 4; ds++) {
            bf4_t ov;
            #pragma unroll
            for (int r = 0; r < 4; r++) ov[r] = (__bf16)(o[ds][r] * inv);
            *reinterpret_cast<bf4_t*>(Zb + zrow + ds * 16 + quad * 4) = ov;
        }
    }
}

// ---------------------------------------------------------------- launch
extern "C" void kernel_launch(void* const* d_in, const int* in_sizes, int n_in,
                              void* d_out, int out_size, void* d_ws, size_t ws_size,
                              hipStream_t stream)
{
    (void)in_sizes; (void)n_in; (void)out_size; (void)ws_size;

    const float* embed = (const float*)d_in[0];
    const int*   mask  = (const int*)d_in[1];
    const float* Wq = (const float*)d_in[2];
    const float* bq = (const float*)d_in[3];
    const float* Wk = (const float*)d_in[4];
    const float* bk = (const float*)d_in[5];
    const float* Wv = (const float*)d_in[6];
    const float* bv = (const float*)d_in[7];
    const float* Wz = (const float*)d_in[8];
    const float* bz = (const float*)d_in[9];
    float* out = (float*)d_out;

    char* ws = (char*)d_ws;
    const size_t MB = (size_t)1024 * 1024;
    __bf16*   WqT = (__bf16*)(ws + 0 * MB);
    __bf16*   WkT = (__bf16*)(ws + 2 * MB);
    __bf16*   WvT = (__bf16*)(ws + 4 * MB);
    __bf16*   WzT = (__bf16*)(ws + 6 * MB);
    __bf16*   Eb  = (__bf16*)(ws + 8 * MB);
    __bf16*   Qb  = (__bf16*)(ws + 16 * MB);
    __bf16*   Kb  = (__bf16*)(ws + 24 * MB);
    __bf16*   Vb  = (__bf16*)(ws + 32 * MB);
    __bf16*   Zb  = (__bf16*)(ws + 40 * MB);
    unsigned* Mb  = (unsigned*)(ws + 48 * MB);   // bitmask, 1MB -> total 49MB

    prep_kernel<<<dim3(6144), 256, 0, stream>>>(embed, mask, Wq, Wk, Wv, Wz,
                                                WqT, WkT, WvT, WzT, Eb, Mb);
    gemm_qkv_kernel<<<dim3(8, 32, 3), 256, 0, stream>>>(Eb, WqT, WkT, WvT,
                                                        bq, bk, bv, Qb, Kb, Vb);
    flash_kernel<<<dim3(32, Hh, Bb), 512, 0, stream>>>(Qb, Kb, Vb, Mb, Zb);
    gemm_out_kernel<<<dim3(8, 64, 1), 256, 0, stream>>>(Zb, WzT, bz, out);
}

// Round 4
// 226.862 us; speedup vs baseline: 1.2441x; 1.2441x over previous
//
#include <hip/hip_runtime.h>
#include <hip/hip_bf16.h>

// B=2, T=2048, E=1024, H=16, D=64. Inputs f32 (+ int32 mask), output f32.
// Internal bf16 MFMA pipeline.
// prep: ONE dispatch = embed f32->bf16 convert + 4x weight transpose+cast
//       + mask int32 -> 1-bit bitmask (1MB, L2-resident).
// GEMMs: round-7 ASYNC16 2-barrier structure verbatim (known good).
// Flash: wave-pair key-split at 512 threads (partition verified correct in
//   rounds 2+3). ROUND-4 FIX: __launch_bounds__(512,6) -- round 3's (512,8)
//   hard-capped VGPR at 64/wave (m69: 8 waves/SIMD needs <=64), allocator
//   split 32 VGPR + spilled (WRITE_SIZE 36.9MB of scratch). Cap 6 waves/EU
//   = ~85 VGPR budget: fits the ~60-70 reg working set with NO spill, still
//   3 blocks/CU guaranteed (4 if allocation lands <=64). LDS 40960B.

typedef __bf16 bf8_t  __attribute__((ext_vector_type(8)));
typedef __bf16 bf4_t  __attribute__((ext_vector_type(4)));
typedef float  f4_t   __attribute__((ext_vector_type(4)));

constexpr int Bb = 2, Tt = 2048, Hh = 16, Dd = 64;

#define ASYNC16(g, l)                                                        \
    __builtin_amdgcn_global_load_lds(                                        \
        (const __attribute__((address_space(1))) void*)(g),                  \
        (__attribute__((address_space(3))) void*)(l), 16, 0, 0)

#if __has_builtin(__builtin_amdgcn_exp2f)
#define EXP2F(x) __builtin_amdgcn_exp2f(x)
#else
#define EXP2F(x) exp2f(x)
#endif

// ---------------------------------------------------------------- prep
// blockIdx.x decode: [0,4096) transpose W (z>>10 = which matrix),
// [4096,5120) convert embed, [5120,6144) build bitmask.
__global__ __launch_bounds__(256) void prep_kernel(
    const float* __restrict__ embed, const int* __restrict__ mask,
    const float* __restrict__ w0, const float* __restrict__ w1,
    const float* __restrict__ w2, const float* __restrict__ w3,
    __bf16* __restrict__ o0, __bf16* __restrict__ o1,
    __bf16* __restrict__ o2, __bf16* __restrict__ o3,
    __bf16* __restrict__ Eb, unsigned* __restrict__ Mbits)
{
    int z = blockIdx.x;
    if (z < 4096) {
        const float* in; __bf16* out;
        switch (z >> 10) {
            case 0: in = w0; out = o0; break;
            case 1: in = w1; out = o1; break;
            case 2: in = w2; out = o2; break;
            default: in = w3; out = o3; break;
        }
        int rem = z & 1023;
        int bx = (rem & 31) * 32;      // n offset
        int by = (rem >> 5) * 32;      // k offset
        __shared__ float t[32][33];
        int x  = threadIdx.x & 31;
        int y0 = threadIdx.x >> 5;
        #pragma unroll
        for (int i = 0; i < 4; i++) {
            int y = y0 + i * 8;
            t[y][x] = in[(size_t)(by + y) * 1024 + bx + x];
        }
        __syncthreads();
        #pragma unroll
        for (int i = 0; i < 4; i++) {
            int y = y0 + i * 8;
            out[(size_t)(bx + y) * 1024 + by + x] = (__bf16)t[x][y];
        }
    } else if (z < 5120) {
        size_t base = (size_t)(z - 4096) * 4096;
        #pragma unroll
        for (int j = 0; j < 4; j++) {
            size_t i = base + j * 1024 + threadIdx.x * 4;
            float4 v = *reinterpret_cast<const float4*>(embed + i);
            bf4_t o = {(__bf16)v.x, (__bf16)v.y, (__bf16)v.z, (__bf16)v.w};
            *reinterpret_cast<bf4_t*>(Eb + i) = o;
        }
    } else {
        // word g covers mask[g*32 .. g*32+32)
        size_t g = (size_t)(z - 5120) * 256 + threadIdx.x;
        const int* mp = mask + g * 32;
        unsigned v = 0;
        #pragma unroll
        for (int i = 0; i < 8; i++) {
            int4 m4 = *reinterpret_cast<const int4*>(mp + i * 4);
            if (m4.x) v |= 1u << (i * 4 + 0);
            if (m4.y) v |= 1u << (i * 4 + 1);
            if (m4.z) v |= 1u << (i * 4 + 2);
            if (m4.w) v |= 1u << (i * 4 + 3);
        }
        Mbits[g] = v;
    }
}

// ---------------------------------------------------------------- GEMM body
// round-7 structure verbatim: ASYNC16 staging, 2 barriers/iter, XOR swizzle.
template <int TM, typename OutT>
__device__ __forceinline__ void gemm_body(const __bf16* __restrict__ A,
                                          const __bf16* __restrict__ Bt,
                                          const float* __restrict__ bias,
                                          OutT* __restrict__ out,
                                          int mode, float oscale, int bx, int by)
{
    constexpr int NI = TM / 32;
    alignas(16) __shared__ __bf16 As[TM * 64];
    alignas(16) __shared__ __bf16 Bs[128 * 64];

    int tid  = threadIdx.x;
    int lane = tid & 63;
    int quad = lane >> 4;
    int l16  = lane & 15;
    int wave = tid >> 6;
    int wm   = wave >> 1, wn = wave & 1;

    f4_t acc[NI][4];
    #pragma unroll
    for (int i = 0; i < NI; i++)
        #pragma unroll
        for (int j = 0; j < 4; j++)
            acc[i][j] = f4_t{0.f, 0.f, 0.f, 0.f};

    for (int kt = 0; kt < 1024; kt += 64) {
        #pragma unroll
        for (int i = 0; i < TM / 32; i++) {
            int c   = tid + 256 * i;
            int row = c >> 3, j = c & 7;
            ASYNC16(A + (size_t)(by * TM + row) * 1024 + kt + ((j ^ (row & 7)) * 8),
                    &As[c * 8]);
        }
        #pragma unroll
        for (int i = 0; i < 4; i++) {
            int c   = tid + 256 * i;
            int row = c >> 3, j = c & 7;
            ASYNC16(Bt + (size_t)(bx * 128 + row) * 1024 + kt + ((j ^ (row & 7)) * 8),
                    &Bs[c * 8]);
        }
        __syncthreads();

        bf8_t af[2][NI], bfr[2][4];
        #pragma unroll
        for (int c = 0; c < 2; c++) {
            #pragma unroll
            for (int im = 0; im < NI; im++) {
                int row = wm * (TM / 2) + im * 16 + l16;
                af[c][im] = *reinterpret_cast<const bf8_t*>(
                    &As[row * 64 + (((c * 4 + quad) ^ (row & 7)) * 8)]);
            }
            #pragma unroll
            for (int in_ = 0; in_ < 4; in_++) {
                int row = wn * 64 + in_ * 16 + l16;
                bfr[c][in_] = *reinterpret_cast<const bf8_t*>(
                    &Bs[row * 64 + (((c * 4 + quad) ^ (row & 7)) * 8)]);
            }
        }
        #pragma unroll
        for (int c = 0; c < 2; c++)
            #pragma unroll
            for (int im = 0; im < NI; im++)
                #pragma unroll
                for (int in_ = 0; in_ < 4; in_++)
                    acc[im][in_] = __builtin_amdgcn_mfma_f32_16x16x32_bf16(
                        af[c][im], bfr[c][in_], acc[im][in_], 0, 0, 0);
        __syncthreads();
    }

    #pragma unroll
    for (int im = 0; im < NI; im++) {
        #pragma unroll
        for (int in_ = 0; in_ < 4; in_++) {
            int gc  = bx * 128 + wn * 64 + in_ * 16 + l16;
            float bb = bias[gc];
            int gr0 = by * TM + wm * (TM / 2) + im * 16 + quad * 4;
            if (mode == 2) {
                int b = gr0 >> 11, t0 = gr0 & 2047;
                int h = gc >> 6,  d = gc & 63;
                bf4_t ov;
                #pragma unroll
                for (int r = 0; r < 4; r++)
                    ov[r] = (__bf16)(acc[im][in_][r] + bb);
                *reinterpret_cast<bf4_t*>(
                    (__bf16*)out + ((size_t)(b * Hh + h) * Dd + d) * Tt + t0) = ov;
            } else {
                #pragma unroll
                for (int r = 0; r < 4; r++) {
                    int gr  = gr0 + r;
                    float v = (acc[im][in_][r] + bb) * oscale;
                    size_t idx;
                    if (mode == 0) {
                        idx = (size_t)gr * 1024 + gc;
                    } else {
                        int b = gr >> 11, t = gr & 2047;
                        int h = gc >> 6,  d = gc & 63;
                        idx = ((size_t)(b * Hh + h) * Tt + t) * Dd + d;
                    }
                    out[idx] = (OutT)v;
                }
            }
        }
    }
}

__global__ __launch_bounds__(256) void gemm_qkv_kernel(
    const __bf16* __restrict__ A,
    const __bf16* __restrict__ WqT, const __bf16* __restrict__ WkT, const __bf16* __restrict__ WvT,
    const float* __restrict__ bq,  const float* __restrict__ bk,  const float* __restrict__ bv,
    __bf16* __restrict__ Qo, __bf16* __restrict__ Ko, __bf16* __restrict__ Vo)
{
    const __bf16* Bt; const float* bias; __bf16* out; int mode; float sc;
    // Q carries 0.125 * log2(e) so flash softmax runs in exp2 domain.
    if      (blockIdx.z == 0) { Bt = WqT; bias = bq; out = Qo; mode = 1; sc = 0.18033688011112042f; }
    else if (blockIdx.z == 1) { Bt = WkT; bias = bk; out = Ko; mode = 1; sc = 1.f; }
    else                      { Bt = WvT; bias = bv; out = Vo; mode = 2; sc = 1.f; }
    gemm_body<128, __bf16>(A, Bt, bias, out, mode, sc, blockIdx.x, blockIdx.y);
}

__global__ __launch_bounds__(256) void gemm_out_kernel(
    const __bf16* __restrict__ A, const __bf16* __restrict__ Bt,
    const float* __restrict__ bias, float* __restrict__ out)
{
    gemm_body<64, float>(A, Bt, bias, out, 0, 1.f, blockIdx.x, blockIdx.y);
}

// ---------------------------------------------------------------- flash attn
// Wave-pair key-split, 512 thr = 8 waves. grid (T/64, H, B) = 1024 blocks.
// wave w: q-strip s = w>>1 (16 rows), key-half hk = w&1 (32 of 64 keys).
// LDS exactly 40960B:
//   Ks[2][64*64] 16KB | Vs[2][64*64] 16KB | P[4 strips][16*64] 8KB (XOR swz)
// Dbuf K/V, one barrier/iter, reg-staged prefetch after the barrier.
// P is intra-wave (own 32-col half) -> no extra barriers.
// Partial O/l pair-combined via LDS (reusing K/V region) at the end.
// launch_bounds (512,6): ~85-VGPR cap, no spill (round 3's (512,8) forced
// 64-cap -> 32 VGPR + 29MB scratch writes).
__global__ __launch_bounds__(512, 6) void flash_kernel(
    const __bf16* __restrict__ Qb, const __bf16* __restrict__ Kb,
    const __bf16* __restrict__ Vb, const unsigned* __restrict__ Mbits,
    __bf16* __restrict__ Zb)
{
    alignas(16) __shared__ char smem[40960];
    __bf16* Ks  = (__bf16*)smem;
    __bf16* Vs  = (__bf16*)(smem + 16384);
    char*   Pb  = smem + 32768;          // byte-addressed, XOR-swizzled
    float*  fscr = (float*)smem;         // epilogue reuse of K/V region

    int tid  = threadIdx.x;
    int lane = tid & 63;
    int wave = tid >> 6;        // 0..7
    int s    = wave >> 1;       // q-strip 0..3
    int hk   = wave & 1;        // key half
    int quad = lane >> 4;
    int l16  = lane & 15;
    int b = blockIdx.z, h = blockIdx.y;
    int bh = b * Hh + h;
    int qrow = blockIdx.x * 64 + s * 16;

    // staging: 512 threads cover one 64x64 tile; each thread 16B K + 16B V
    int srow = tid >> 3, sj = tid & 7;
    const __bf16* kgp = Kb + ((size_t)bh * Tt + srow) * Dd + ((sj ^ (srow & 7)) * 8);
    const __bf16* vgp = Vb + ((size_t)bh * Dd + srow) * Tt + ((sj ^ (srow & 7)) * 8);
    const int sdst = tid * 8;

    bf8_t qf[2];
    #pragma unroll
    for (int c = 0; c < 2; c++)
        qf[c] = *reinterpret_cast<const bf8_t*>(
            Qb + ((size_t)bh * Tt + qrow + l16) * Dd + c * 32 + quad * 8);

    // ones-fragment for the l_i row-sum MFMA
    bf8_t ones;
    #pragma unroll
    for (int i = 0; i < 8; i++) ones[i] = (__bf16)1.0f;

    // bitmask row for this lane's query
    const unsigned* bmp = Mbits + ((size_t)b * Tt + qrow + l16) * 64;

    // P byte offsets (stride 64 bf16 = 128B/row, XOR swizzle on 16B slots).
    // write n2: col2 = hk*64 + n2*32 + quad*8 (bf4); read: col2 = hk*64+quad*16 (bf8)
    char* pws = Pb + s * 2048;
    const int pw0 = l16 * 128 + ((hk * 64 + quad * 8)      ^ ((l16 & 7) << 4));
    const int pw1 = l16 * 128 + ((hk * 64 + 32 + quad * 8) ^ ((l16 & 7) << 4));
    const int prd = l16 * 128 + ((hk * 64 + quad * 16)     ^ ((l16 & 7) << 4));

    f4_t lacc = f4_t{0.f, 0.f, 0.f, 0.f};
    f4_t o[4];
    #pragma unroll
    for (int d = 0; d < 4; d++) o[d] = f4_t{0.f, 0.f, 0.f, 0.f};

    // prime: tile 0 into regs
    bf8_t kreg = *reinterpret_cast<const bf8_t*>(kgp);
    bf8_t vreg = *reinterpret_cast<const bf8_t*>(vgp);
    unsigned long long mreg = *reinterpret_cast<const unsigned long long*>(bmp);

    for (int kt = 0; kt < Tt; kt += 64) {
        int par = (kt >> 6) & 1;
        *reinterpret_cast<bf8_t*>(&Ks[par * 4096 + sdst]) = kreg;
        *reinterpret_cast<bf8_t*>(&Vs[par * 4096 + sdst]) = vreg;
        // this wave's mask nibbles (keys hk*32 + n2*16 + quad*4 + r)
        unsigned nib0 = (unsigned)(mreg >> (hk * 32 + quad * 4)) & 0xFu;
        unsigned nib1 = (unsigned)(mreg >> (hk * 32 + 16 + quad * 4)) & 0xFu;
        __syncthreads();

        // prefetch next tile (issued after barrier -> hidden under compute)
        int ktn = (kt + 64 < Tt) ? kt + 64 : 0;
        kreg = *reinterpret_cast<const bf8_t*>(kgp + (size_t)ktn * Dd);
        vreg = *reinterpret_cast<const bf8_t*>(vgp + ktn);
        mreg = *reinterpret_cast<const unsigned long long*>(bmp + (ktn >> 5));

        // S^T = K Q^T over this wave's 32 keys: 2 key-subtiles x 2 d-chunks
        f4_t sA = f4_t{0.f, 0.f, 0.f, 0.f};
        f4_t sB = f4_t{0.f, 0.f, 0.f, 0.f};
        __builtin_amdgcn_s_setprio(1);
        #pragma unroll
        for (int c = 0; c < 2; c++) {
            int krow0 = hk * 32 + l16;
            bf8_t kf0 = *reinterpret_cast<const bf8_t*>(
                &Ks[par * 4096 + krow0 * 64 + (((c * 4 + quad) ^ (krow0 & 7)) * 8)]);
            sA = __builtin_amdgcn_mfma_f32_16x16x32_bf16(kf0, qf[c], sA, 0, 0, 0);
            int krow1 = hk * 32 + 16 + l16;
            bf8_t kf1 = *reinterpret_cast<const bf8_t*>(
                &Ks[par * 4096 + krow1 * 64 + (((c * 4 + quad) ^ (krow1 & 7)) * 8)]);
            sB = __builtin_amdgcn_mfma_f32_16x16x32_bf16(kf1, qf[c], sB, 0, 0, 0);
        }
        __builtin_amdgcn_s_setprio(0);

        // p = mask-bit ? exp2(s) : 0 ; write this wave's 32-col P half
        {
            bf4_t pv4;
            #pragma unroll
            for (int r = 0; r < 4; r++) {
                float p = (nib0 & (1u << r)) ? EXP2F(sA[r]) : 0.f;
                pv4[r] = (__bf16)p;
            }
            *reinterpret_cast<bf4_t*>(pws + pw0) = pv4;
            #pragma unroll
            for (int r = 0; r < 4; r++) {
                float p = (nib1 & (1u << r)) ? EXP2F(sB[r]) : 0.f;
                pv4[r] = (__bf16)p;
            }
            *reinterpret_cast<bf4_t*>(pws + pw1) = pv4;
        }

        // O_half += V^T @ P_half ; l_half += ones @ P_half (intra-wave LDS dep)
        bf8_t pf = *reinterpret_cast<const bf8_t*>(pws + prd);
        __builtin_amdgcn_s_setprio(1);
        lacc = __builtin_amdgcn_mfma_f32_16x16x32_bf16(ones, pf, lacc, 0, 0, 0);
        #pragma unroll
        for (int ds = 0; ds < 4; ds++) {
            int vrow = ds * 16 + l16;
            bf8_t vf = *reinterpret_cast<const bf8_t*>(
                &Vs[par * 4096 + vrow * 64 + (((hk * 4 + quad) ^ (vrow & 7)) * 8)]);
            o[ds] = __builtin_amdgcn_mfma_f32_16x16x32_bf16(vf, pf, o[ds], 0, 0, 0);
        }
        __builtin_amdgcn_s_setprio(0);
        // no trailing barrier: next iter writes the other buffer.
    }

    // pair-combine: hk=1 wave dumps partial O and l to LDS; hk=0 adds + stores
    __syncthreads();
    float* wsp = fscr + s * (64 * 20);
    if (hk) {
        #pragma unroll
        for (int ds = 0; ds < 4; ds++)
            *reinterpret_cast<f4_t*>(&wsp[lane * 20 + ds * 4]) = o[ds];
        wsp[lane * 20 + 16] = lacc[0];
    }
    __syncthreads();
    if (!hk) {
        #pragma unroll
        for (int ds = 0; ds < 4; ds++) {
            f4_t op = *reinterpret_cast<const f4_t*>(&wsp[lane * 20 + ds * 4]);
            o[ds] += op;
        }
        float l = lacc[0] + wsp[lane * 20 + 16];
        float inv = 1.f / fmaxf(l, 1e-30f);
        size_t zrow = ((size_t)b * Tt + qrow + l16) * 1024 + h * 64;
        #pragma unroll
        for (int ds = 0; ds < 4; ds++) {
            bf4_t ov;
            #pragma unroll
            for (int r = 0; r < 4; r++) ov[r] = (__bf16)(o[ds][r] * inv);
            *reinterpret_cast<bf4_t*>(Zb + zrow + ds * 16 + quad * 4) = ov;
        }
    }
}

// ---------------------------------------------------------------- launch
extern "C" void kernel_launch(void* const* d_in, const int* in_sizes, int n_in,
                              void* d_out, int out_size, void* d_ws, size_t ws_size,
                              hipStream_t stream)
{
    (void)in_sizes; (void)n_in; (void)out_size; (void)ws_size;

    const float* embed = (const float*)d_in[0];
    const int*   mask  = (const int*)d_in[1];
    const float* Wq = (const float*)d_in[2];
    const float* bq = (const float*)d_in[3];
    const float* Wk = (const float*)d_in[4];
    const float* bk = (const float*)d_in[5];
    const float* Wv = (const float*)d_in[6];
    const float* bv = (const float*)d_in[7];
    const float* Wz = (const float*)d_in[8];
    const float* bz = (const float*)d_in[9];
    float* out = (float*)d_out;

    char* ws = (char*)d_ws;
    const size_t MB = (size_t)1024 * 1024;
    __bf16*   WqT = (__bf16*)(ws + 0 * MB);
    __bf16*   WkT = (__bf16*)(ws + 2 * MB);
    __bf16*   WvT = (__bf16*)(ws + 4 * MB);
    __bf16*   WzT = (__bf16*)(ws + 6 * MB);
    __bf16*   Eb  = (__bf16*)(ws + 8 * MB);
    __bf16*   Qb  = (__bf16*)(ws + 16 * MB);
    __bf16*   Kb  = (__bf16*)(ws + 24 * MB);
    __bf16*   Vb  = (__bf16*)(ws + 32 * MB);
    __bf16*   Zb  = (__bf16*)(ws + 40 * MB);
    unsigned* Mb  = (unsigned*)(ws + 48 * MB);   // bitmask, 1MB -> total 49MB

    prep_kernel<<<dim3(6144), 256, 0, stream>>>(embed, mask, Wq, Wk, Wv, Wz,
                                                WqT, WkT, WvT, WzT, Eb, Mb);
    gemm_qkv_kernel<<<dim3(8, 32, 3), 256, 0, stream>>>(Eb, WqT, WkT, WvT,
                                                        bq, bk, bv, Qb, Kb, Vb);
    flash_kernel<<<dim3(32, Hh, Bb), 512, 0, stream>>>(Qb, Kb, Vb, Mb, Zb);
    gemm_out_kernel<<<dim3(8, 64, 1), 256, 0, stream>>>(Zb, WzT, bz, out);
}

// Round 5
// 225.619 us; speedup vs baseline: 1.2510x; 1.0055x over previous
//
#include <hip/hip_runtime.h>
#include <hip/hip_bf16.h>

// B=2, T=2048, E=1024, H=16, D=64. Inputs f32 (+ int32 mask), output f32.
// Internal bf16 MFMA pipeline.
// prep: ONE dispatch = embed f32->bf16 convert + 4x weight transpose+cast
//       + mask int32 -> 1-bit bitmask (1MB, L2-resident).
// qkv GEMM: round-7 ASYNC16 2-barrier structure verbatim (known good).
// Flash: ROUND-1 KERNEL VERBATIM (measured 65.6us): 512 thr, q-tile 128,
//   8 waves x 16-row strips, full 64-key tiles per wave, ones-MFMA l_i,
//   setprio around MFMA clusters. Rounds 2-4 proved the key-split
//   restructure net-negative (2x staging overhead > occupancy gain).
// out GEMM THIS ROUND: 64x64 tile, grid (16,64)=1024 blocks = 4 blocks/CU
//   (was 512 = 2/CU, grid-limited at 8 waves/CU). Doubles resident waves
//   on a latency-bound kernel; MFMA:stage ratio drops 16:6 -> 8:4 but
//   the kernel is not throughput-limited.

typedef __bf16 bf8_t  __attribute__((ext_vector_type(8)));
typedef __bf16 bf4_t  __attribute__((ext_vector_type(4)));
typedef float  f4_t   __attribute__((ext_vector_type(4)));

constexpr int Bb = 2, Tt = 2048, Hh = 16, Dd = 64;

#define ASYNC16(g, l)                                                        \
    __builtin_amdgcn_global_load_lds(                                        \
        (const __attribute__((address_space(1))) void*)(g),                  \
        (__attribute__((address_space(3))) void*)(l), 16, 0, 0)

#if __has_builtin(__builtin_amdgcn_exp2f)
#define EXP2F(x) __builtin_amdgcn_exp2f(x)
#else
#define EXP2F(x) exp2f(x)
#endif

// ---------------------------------------------------------------- prep
// blockIdx.x decode: [0,4096) transpose W (z>>10 = which matrix),
// [4096,5120) convert embed, [5120,6144) build bitmask.
__global__ __launch_bounds__(256) void prep_kernel(
    const float* __restrict__ embed, const int* __restrict__ mask,
    const float* __restrict__ w0, const float* __restrict__ w1,
    const float* __restrict__ w2, const float* __restrict__ w3,
    __bf16* __restrict__ o0, __bf16* __restrict__ o1,
    __bf16* __restrict__ o2, __bf16* __restrict__ o3,
    __bf16* __restrict__ Eb, unsigned* __restrict__ Mbits)
{
    int z = blockIdx.x;
    if (z < 4096) {
        const float* in; __bf16* out;
        switch (z >> 10) {
            case 0: in = w0; out = o0; break;
            case 1: in = w1; out = o1; break;
            case 2: in = w2; out = o2; break;
            default: in = w3; out = o3; break;
        }
        int rem = z & 1023;
        int bx = (rem & 31) * 32;      // n offset
        int by = (rem >> 5) * 32;      // k offset
        __shared__ float t[32][33];
        int x  = threadIdx.x & 31;
        int y0 = threadIdx.x >> 5;
        #pragma unroll
        for (int i = 0; i < 4; i++) {
            int y = y0 + i * 8;
            t[y][x] = in[(size_t)(by + y) * 1024 + bx + x];
        }
        __syncthreads();
        #pragma unroll
        for (int i = 0; i < 4; i++) {
            int y = y0 + i * 8;
            out[(size_t)(bx + y) * 1024 + by + x] = (__bf16)t[x][y];
        }
    } else if (z < 5120) {
        size_t base = (size_t)(z - 4096) * 4096;
        #pragma unroll
        for (int j = 0; j < 4; j++) {
            size_t i = base + j * 1024 + threadIdx.x * 4;
            float4 v = *reinterpret_cast<const float4*>(embed + i);
            bf4_t o = {(__bf16)v.x, (__bf16)v.y, (__bf16)v.z, (__bf16)v.w};
            *reinterpret_cast<bf4_t*>(Eb + i) = o;
        }
    } else {
        // word g covers mask[g*32 .. g*32+32)
        size_t g = (size_t)(z - 5120) * 256 + threadIdx.x;
        const int* mp = mask + g * 32;
        unsigned v = 0;
        #pragma unroll
        for (int i = 0; i < 8; i++) {
            int4 m4 = *reinterpret_cast<const int4*>(mp + i * 4);
            if (m4.x) v |= 1u << (i * 4 + 0);
            if (m4.y) v |= 1u << (i * 4 + 1);
            if (m4.z) v |= 1u << (i * 4 + 2);
            if (m4.w) v |= 1u << (i * 4 + 3);
        }
        Mbits[g] = v;
    }
}

// ---------------------------------------------------------------- GEMM body
// round-7 structure verbatim: ASYNC16 staging, 2 barriers/iter, XOR swizzle.
template <int TM, typename OutT>
__device__ __forceinline__ void gemm_body(const __bf16* __restrict__ A,
                                          const __bf16* __restrict__ Bt,
                                          const float* __restrict__ bias,
                                          OutT* __restrict__ out,
                                          int mode, float oscale, int bx, int by)
{
    constexpr int NI = TM / 32;
    alignas(16) __shared__ __bf16 As[TM * 64];
    alignas(16) __shared__ __bf16 Bs[128 * 64];

    int tid  = threadIdx.x;
    int lane = tid & 63;
    int quad = lane >> 4;
    int l16  = lane & 15;
    int wave = tid >> 6;
    int wm   = wave >> 1, wn = wave & 1;

    f4_t acc[NI][4];
    #pragma unroll
    for (int i = 0; i < NI; i++)
        #pragma unroll
        for (int j = 0; j < 4; j++)
            acc[i][j] = f4_t{0.f, 0.f, 0.f, 0.f};

    for (int kt = 0; kt < 1024; kt += 64) {
        #pragma unroll
        for (int i = 0; i < TM / 32; i++) {
            int c   = tid + 256 * i;
            int row = c >> 3, j = c & 7;
            ASYNC16(A + (size_t)(by * TM + row) * 1024 + kt + ((j ^ (row & 7)) * 8),
                    &As[c * 8]);
        }
        #pragma unroll
        for (int i = 0; i < 4; i++) {
            int c   = tid + 256 * i;
            int row = c >> 3, j = c & 7;
            ASYNC16(Bt + (size_t)(bx * 128 + row) * 1024 + kt + ((j ^ (row & 7)) * 8),
                    &Bs[c * 8]);
        }
        __syncthreads();

        bf8_t af[2][NI], bfr[2][4];
        #pragma unroll
        for (int c = 0; c < 2; c++) {
            #pragma unroll
            for (int im = 0; im < NI; im++) {
                int row = wm * (TM / 2) + im * 16 + l16;
                af[c][im] = *reinterpret_cast<const bf8_t*>(
                    &As[row * 64 + (((c * 4 + quad) ^ (row & 7)) * 8)]);
            }
            #pragma unroll
            for (int in_ = 0; in_ < 4; in_++) {
                int row = wn * 64 + in_ * 16 + l16;
                bfr[c][in_] = *reinterpret_cast<const bf8_t*>(
                    &Bs[row * 64 + (((c * 4 + quad) ^ (row & 7)) * 8)]);
            }
        }
        #pragma unroll
        for (int c = 0; c < 2; c++)
            #pragma unroll
            for (int im = 0; im < NI; im++)
                #pragma unroll
                for (int in_ = 0; in_ < 4; in_++)
                    acc[im][in_] = __builtin_amdgcn_mfma_f32_16x16x32_bf16(
                        af[c][im], bfr[c][in_], acc[im][in_], 0, 0, 0);
        __syncthreads();
    }

    #pragma unroll
    for (int im = 0; im < NI; im++) {
        #pragma unroll
        for (int in_ = 0; in_ < 4; in_++) {
            int gc  = bx * 128 + wn * 64 + in_ * 16 + l16;
            float bb = bias[gc];
            int gr0 = by * TM + wm * (TM / 2) + im * 16 + quad * 4;
            if (mode == 2) {
                int b = gr0 >> 11, t0 = gr0 & 2047;
                int h = gc >> 6,  d = gc & 63;
                bf4_t ov;
                #pragma unroll
                for (int r = 0; r < 4; r++)
                    ov[r] = (__bf16)(acc[im][in_][r] + bb);
                *reinterpret_cast<bf4_t*>(
                    (__bf16*)out + ((size_t)(b * Hh + h) * Dd + d) * Tt + t0) = ov;
            } else {
                #pragma unroll
                for (int r = 0; r < 4; r++) {
                    int gr  = gr0 + r;
                    float v = (acc[im][in_][r] + bb) * oscale;
                    size_t idx;
                    if (mode == 0) {
                        idx = (size_t)gr * 1024 + gc;
                    } else {
                        int b = gr >> 11, t = gr & 2047;
                        int h = gc >> 6,  d = gc & 63;
                        idx = ((size_t)(b * Hh + h) * Tt + t) * Dd + d;
                    }
                    out[idx] = (OutT)v;
                }
            }
        }
    }
}

__global__ __launch_bounds__(256) void gemm_qkv_kernel(
    const __bf16* __restrict__ A,
    const __bf16* __restrict__ WqT, const __bf16* __restrict__ WkT, const __bf16* __restrict__ WvT,
    const float* __restrict__ bq,  const float* __restrict__ bk,  const float* __restrict__ bv,
    __bf16* __restrict__ Qo, __bf16* __restrict__ Ko, __bf16* __restrict__ Vo)
{
    const __bf16* Bt; const float* bias; __bf16* out; int mode; float sc;
    // Q carries 0.125 * log2(e) so flash softmax runs in exp2 domain.
    if      (blockIdx.z == 0) { Bt = WqT; bias = bq; out = Qo; mode = 1; sc = 0.18033688011112042f; }
    else if (blockIdx.z == 1) { Bt = WkT; bias = bk; out = Ko; mode = 1; sc = 1.f; }
    else                      { Bt = WvT; bias = bv; out = Vo; mode = 2; sc = 1.f; }
    gemm_body<128, __bf16>(A, Bt, bias, out, mode, sc, blockIdx.x, blockIdx.y);
}

// ---------------------------------------------------------------- out GEMM
// 64x64 tile, grid (16,64) = 1024 blocks = 4 blocks/CU (16 waves/CU).
// Same ASYNC16 2-barrier structure; 4 waves in a 2x2 grid of 32x32
// quadrants; mode-0 epilogue (row-major f32 + bias).
__global__ __launch_bounds__(256) void gemm_out_kernel(
    const __bf16* __restrict__ A, const __bf16* __restrict__ Bt,
    const float* __restrict__ bias, float* __restrict__ out)
{
    alignas(16) __shared__ __bf16 As[64 * 64];
    alignas(16) __shared__ __bf16 Bs[64 * 64];

    int tid  = threadIdx.x;
    int lane = tid & 63;
    int quad = lane >> 4;
    int l16  = lane & 15;
    int wave = tid >> 6;
    int wm   = wave >> 1, wn = wave & 1;
    int bx = blockIdx.x, by = blockIdx.y;

    f4_t acc[2][2];
    #pragma unroll
    for (int i = 0; i < 2; i++)
        #pragma unroll
        for (int j = 0; j < 2; j++)
            acc[i][j] = f4_t{0.f, 0.f, 0.f, 0.f};

    for (int kt = 0; kt < 1024; kt += 64) {
        #pragma unroll
        for (int i = 0; i < 2; i++) {
            int c   = tid + 256 * i;
            int row = c >> 3, j = c & 7;
            ASYNC16(A + (size_t)(by * 64 + row) * 1024 + kt + ((j ^ (row & 7)) * 8),
                    &As[c * 8]);
        }
        #pragma unroll
        for (int i = 0; i < 2; i++) {
            int c   = tid + 256 * i;
            int row = c >> 3, j = c & 7;
            ASYNC16(Bt + (size_t)(bx * 64 + row) * 1024 + kt + ((j ^ (row & 7)) * 8),
                    &Bs[c * 8]);
        }
        __syncthreads();

        bf8_t af[2][2], bfr[2][2];
        #pragma unroll
        for (int c = 0; c < 2; c++) {
            #pragma unroll
            for (int im = 0; im < 2; im++) {
                int row = wm * 32 + im * 16 + l16;
                af[c][im] = *reinterpret_cast<const bf8_t*>(
                    &As[row * 64 + (((c * 4 + quad) ^ (row & 7)) * 8)]);
            }
            #pragma unroll
            for (int in_ = 0; in_ < 2; in_++) {
                int row = wn * 32 + in_ * 16 + l16;
                bfr[c][in_] = *reinterpret_cast<const bf8_t*>(
                    &Bs[row * 64 + (((c * 4 + quad) ^ (row & 7)) * 8)]);
            }
        }
        #pragma unroll
        for (int c = 0; c < 2; c++)
            #pragma unroll
            for (int im = 0; im < 2; im++)
                #pragma unroll
                for (int in_ = 0; in_ < 2; in_++)
                    acc[im][in_] = __builtin_amdgcn_mfma_f32_16x16x32_bf16(
                        af[c][im], bfr[c][in_], acc[im][in_], 0, 0, 0);
        __syncthreads();
    }

    #pragma unroll
    for (int im = 0; im < 2; im++) {
        #pragma unroll
        for (int in_ = 0; in_ < 2; in_++) {
            int gc  = bx * 64 + wn * 32 + in_ * 16 + l16;
            float bb = bias[gc];
            int gr0 = by * 64 + wm * 32 + im * 16 + quad * 4;
            #pragma unroll
            for (int r = 0; r < 4; r++)
                out[(size_t)(gr0 + r) * 1024 + gc] = acc[im][in_][r] + bb;
        }
    }
}

// ---------------------------------------------------------------- flash attn
// Round-1 kernel verbatim (measured 65.6us). grid (T/128, H, B), 512 thr =
// 8 waves x 16-row q-strips, full 64-key tiles. Dbuf LDS, one barrier/iter,
// reg-staged K/V prefetch issued after the barrier. Mask via u64 bitmask.
// l_i via MFMA with ones-fragment; setprio(1) around MFMA clusters.
__global__ __launch_bounds__(512, 4) void flash_kernel(
    const __bf16* __restrict__ Qb, const __bf16* __restrict__ Kb,
    const __bf16* __restrict__ Vb, const unsigned* __restrict__ Mbits,
    __bf16* __restrict__ Zb)
{
    alignas(16) __shared__ __bf16 Ks[2][64 * 64];   // swizzled, 8KB each
    alignas(16) __shared__ __bf16 Vs[2][64 * 64];
    alignas(16) __shared__ __bf16 Ps[8 * 16 * 72];  // per-wave P^T, 18KB

    int tid  = threadIdx.x;
    int lane = tid & 63;
    int wave = tid >> 6;
    int quad = lane >> 4;
    int l16  = lane & 15;
    int b = blockIdx.z, h = blockIdx.y;
    int bh = b * Hh + h;
    int qrow = blockIdx.x * 128 + wave * 16;

    int srow = tid >> 3, sj = tid & 7;
    const __bf16* kgp = Kb + ((size_t)bh * Tt + srow) * Dd + ((sj ^ (srow & 7)) * 8);
    const __bf16* vgp = Vb + ((size_t)bh * Dd + srow) * Tt + ((sj ^ (srow & 7)) * 8);
    const int sdst = tid * 8;

    bf8_t qf[2];
    #pragma unroll
    for (int c = 0; c < 2; c++)
        qf[c] = *reinterpret_cast<const bf8_t*>(
            Qb + ((size_t)bh * Tt + qrow + l16) * Dd + c * 32 + quad * 8);

    // ones-fragment for the l_i row-sum MFMA (A = all-ones 16x32 tile)
    bf8_t ones;
    #pragma unroll
    for (int i = 0; i < 8; i++) ones[i] = (__bf16)1.0f;

    // bitmask row for this lane's query: 64 words/row, u64 per 64-key tile
    const unsigned* bmp = Mbits + ((size_t)b * Tt + qrow + l16) * 64;

    f4_t lacc = f4_t{0.f, 0.f, 0.f, 0.f};
    f4_t o[4];
    #pragma unroll
    for (int d = 0; d < 4; d++) o[d] = f4_t{0.f, 0.f, 0.f, 0.f};

    __bf16* pw = Ps + wave * 16 * 72;

    // prime: tile 0 into regs
    bf8_t kreg = *reinterpret_cast<const bf8_t*>(kgp);
    bf8_t vreg = *reinterpret_cast<const bf8_t*>(vgp);
    unsigned long long mreg = *reinterpret_cast<const unsigned long long*>(bmp);

    for (int kt = 0; kt < Tt; kt += 64) {
        int par = (kt >> 6) & 1;
        *reinterpret_cast<bf8_t*>(&Ks[par][sdst]) = kreg;
        *reinterpret_cast<bf8_t*>(&Vs[par][sdst]) = vreg;
        // per-n 4-bit nibbles for this lane's quad, captured before reload
        unsigned nib[4];
        #pragma unroll
        for (int n = 0; n < 4; n++)
            nib[n] = (unsigned)(mreg >> (n * 16 + quad * 4)) & 0xFu;
        __syncthreads();

        // prefetch next tile (issued after barrier -> not drained by it)
        int ktn = (kt + 64 < Tt) ? kt + 64 : 0;
        kreg = *reinterpret_cast<const bf8_t*>(kgp + (size_t)ktn * Dd);
        vreg = *reinterpret_cast<const bf8_t*>(vgp + ktn);
        mreg = *reinterpret_cast<const unsigned long long*>(bmp + (ktn >> 5));

        // S^T = K Q^T : 4 key-subtiles x 2 d-chunks
        f4_t s[4];
        #pragma unroll
        for (int n = 0; n < 4; n++) s[n] = f4_t{0.f, 0.f, 0.f, 0.f};
        __builtin_amdgcn_s_setprio(1);
        #pragma unroll
        for (int c = 0; c < 2; c++)
            #pragma unroll
            for (int n = 0; n < 4; n++) {
                int krow = n * 16 + l16;
                bf8_t kf = *reinterpret_cast<const bf8_t*>(
                    &Ks[par][krow * 64 + (((c * 4 + quad) ^ (krow & 7)) * 8)]);
                s[n] = __builtin_amdgcn_mfma_f32_16x16x32_bf16(kf, qf[c], s[n], 0, 0, 0);
            }
        __builtin_amdgcn_s_setprio(0);

        // p = mask-bit ? exp2(s) : 0; P^T -> LDS (row-sum via MFMA below)
        #pragma unroll
        for (int n = 0; n < 4; n++) {
            bf4_t pv4;
            #pragma unroll
            for (int r = 0; r < 4; r++) {
                float p = (nib[n] & (1u << r)) ? EXP2F(s[n][r]) : 0.f;
                pv4[r] = (__bf16)p;
            }
            *reinterpret_cast<bf4_t*>(&pw[l16 * 72 + n * 16 + quad * 4]) = pv4;
        }

        // O^T += V^T @ P^T over 64 keys (2 chunks); l_i += ones @ P^T
        __builtin_amdgcn_s_setprio(1);
        #pragma unroll
        for (int c = 0; c < 2; c++) {
            bf8_t pf = *reinterpret_cast<const bf8_t*>(
                &pw[l16 * 72 + c * 32 + quad * 8]);
            lacc = __builtin_amdgcn_mfma_f32_16x16x32_bf16(ones, pf, lacc, 0, 0, 0);
            #pragma unroll
            for (int ds = 0; ds < 4; ds++) {
                int vrow = ds * 16 + l16;
                bf8_t vf = *reinterpret_cast<const bf8_t*>(
                    &Vs[par][vrow * 64 + (((c * 4 + quad) ^ (vrow & 7)) * 8)]);
                o[ds] = __builtin_amdgcn_mfma_f32_16x16x32_bf16(vf, pf, o[ds], 0, 0, 0);
            }
        }
        __builtin_amdgcn_s_setprio(0);
        // no trailing barrier: next iter writes the other buffer.
    }

    // lacc rows are all identical (ones-fragment): lacc[0] = sum_k P[k][q=l16]
    float inv = 1.f / fmaxf(lacc[0], 1e-30f);
    size_t zrow = ((size_t)b * Tt + qrow + l16) * 1024 + h * 64;
    #pragma unroll
    for (int ds = 0; ds < 4; ds++) {
        bf4_t ov;
        #pragma unroll
        for (int r = 0; r < 4; r++) ov[r] = (__bf16)(o[ds][r] * inv);
        *reinterpret_cast<bf4_t*>(Zb + zrow + ds * 16 + quad * 4) = ov;
    }
}

// ---------------------------------------------------------------- launch
extern "C" void kernel_launch(void* const* d_in, const int* in_sizes, int n_in,
                              void* d_out, int out_size, void* d_ws, size_t ws_size,
                              hipStream_t stream)
{
    (void)in_sizes; (void)n_in; (void)out_size; (void)ws_size;

    const float* embed = (const float*)d_in[0];
    const int*   mask  = (const int*)d_in[1];
    const float* Wq = (const float*)d_in[2];
    const float* bq = (const float*)d_in[3];
    const float* Wk = (const float*)d_in[4];
    const float* bk = (const float*)d_in[5];
    const float* Wv = (const float*)d_in[6];
    const float* bv = (const float*)d_in[7];
    const float* Wz = (const float*)d_in[8];
    const float* bz = (const float*)d_in[9];
    float* out = (float*)d_out;

    char* ws = (char*)d_ws;
    const size_t MB = (size_t)1024 * 1024;
    __bf16*   WqT = (__bf16*)(ws + 0 * MB);
    __bf16*   WkT = (__bf16*)(ws + 2 * MB);
    __bf16*   WvT = (__bf16*)(ws + 4 * MB);
    __bf16*   WzT = (__bf16*)(ws + 6 * MB);
    __bf16*   Eb  = (__bf16*)(ws + 8 * MB);
    __bf16*   Qb  = (__bf16*)(ws + 16 * MB);
    __bf16*   Kb  = (__bf16*)(ws + 24 * MB);
    __bf16*   Vb  = (__bf16*)(ws + 32 * MB);
    __bf16*   Zb  = (__bf16*)(ws + 40 * MB);
    unsigned* Mb  = (unsigned*)(ws + 48 * MB);   // bitmask, 1MB -> total 49MB

    prep_kernel<<<dim3(6144), 256, 0, stream>>>(embed, mask, Wq, Wk, Wv, Wz,
                                                WqT, WkT, WvT, WzT, Eb, Mb);
    gemm_qkv_kernel<<<dim3(8, 32, 3), 256, 0, stream>>>(Eb, WqT, WkT, WvT,
                                                        bq, bk, bv, Qb, Kb, Vb);
    flash_kernel<<<dim3(16, Hh, Bb), 512, 0, stream>>>(Qb, Kb, Vb, Mb, Zb);
    gemm_out_kernel<<<dim3(16, 64), 256, 0, stream>>>(Zb, WzT, bz, out);
}